// Round 4
// baseline (885.575 us; speedup 1.0000x reference)
//
#include <hip/hip_runtime.h>
#include <stdint.h>

typedef _Float16 f16;
typedef _Float16 f16x4 __attribute__((ext_vector_type(4)));
typedef _Float16 f16x8 __attribute__((ext_vector_type(8)));
typedef float    f32x4 __attribute__((ext_vector_type(4)));

#define LO_SCALE 2048.0f

__device__ __forceinline__ void llds16(const void* g, void* l) {
    __builtin_amdgcn_global_load_lds(
        (const __attribute__((address_space(1))) void*)g,
        (__attribute__((address_space(3))) void*)l, 16, 0, 0);
}

__device__ __forceinline__ unsigned long long pack_key(float s, int j) {
    unsigned u = __float_as_uint(s);
    u = (u & 0x80000000u) ? ~u : (u | 0x80000000u);
    return ((unsigned long long)u << 32) | (unsigned)(~(unsigned)j);
}

// ---------------- convert emb -> Bh/Bl fp16 + rinv/2048 ----------------
__global__ void convert_emb_kernel(const float* __restrict__ emb,
                                   f16* __restrict__ bh, f16* __restrict__ bl,
                                   float* __restrict__ rinv, int V, int E) {
    int row  = blockIdx.x * (blockDim.x >> 6) + (threadIdx.x >> 6);
    int lane = threadIdx.x & 63;
    if (row >= V) return;
    const float4* p = (const float4*)(emb + (size_t)row * E);
    int n4 = E >> 2;
    float ss = 0.f;
    for (int i = lane; i < n4; i += 64) {
        float4 v = p[i];
        ss = fmaf(v.x, v.x, ss); ss = fmaf(v.y, v.y, ss);
        ss = fmaf(v.z, v.z, ss); ss = fmaf(v.w, v.w, ss);
    }
    #pragma unroll
    for (int o = 32; o > 0; o >>= 1) ss += __shfl_down(ss, o, 64);
    if (lane == 0) rinv[row] = 1.0f / (sqrtf(ss) * LO_SCALE);

    for (int i = lane; i < n4; i += 64) {
        float4 v = p[i];
        f16x4 h, l;
        h.x = (f16)v.x; l.x = (f16)((v.x - (float)h.x) * LO_SCALE);
        h.y = (f16)v.y; l.y = (f16)((v.y - (float)h.y) * LO_SCALE);
        h.z = (f16)v.z; l.z = (f16)((v.z - (float)h.z) * LO_SCALE);
        h.w = (f16)v.w; l.w = (f16)((v.w - (float)h.w) * LO_SCALE);
        *(f16x4*)&bh[(size_t)row * E + i * 4] = h;
        *(f16x4*)&bl[(size_t)row * E + i * 4] = l;
    }
}

// ---------------- convert batch -> Ahs(=2048*Ah)/Ah/Al ----------------
__global__ void convert_batch_kernel(const float* __restrict__ batch,
                                     f16* __restrict__ ahs, f16* __restrict__ ah,
                                     f16* __restrict__ al, int M, int E) {
    int row  = blockIdx.x * (blockDim.x >> 6) + (threadIdx.x >> 6);
    int lane = threadIdx.x & 63;
    if (row >= M) return;
    const float4* p = (const float4*)(batch + (size_t)row * E);
    int n4 = E >> 2;
    for (int i = lane; i < n4; i += 64) {
        float4 v = p[i];
        f16x4 h, hs, l;
        float t;
        h.x = (f16)v.x; t = (float)h.x * LO_SCALE; t = fminf(fmaxf(t, -65000.f), 65000.f);
        hs.x = (f16)t;  l.x = (f16)((v.x - (float)h.x) * LO_SCALE);
        h.y = (f16)v.y; t = (float)h.y * LO_SCALE; t = fminf(fmaxf(t, -65000.f), 65000.f);
        hs.y = (f16)t;  l.y = (f16)((v.y - (float)h.y) * LO_SCALE);
        h.z = (f16)v.z; t = (float)h.z * LO_SCALE; t = fminf(fmaxf(t, -65000.f), 65000.f);
        hs.z = (f16)t;  l.z = (f16)((v.z - (float)h.z) * LO_SCALE);
        h.w = (f16)v.w; t = (float)h.w * LO_SCALE; t = fminf(fmaxf(t, -65000.f), 65000.f);
        hs.w = (f16)t;  l.w = (f16)((v.w - (float)h.w) * LO_SCALE);
        *(f16x4*)&ahs[(size_t)row * E + i * 4] = hs;
        *(f16x4*)&ah [(size_t)row * E + i * 4] = h;
        *(f16x4*)&al [(size_t)row * E + i * 4] = l;
    }
}

// ---------------- init packed keys ----------------
__global__ void init_keys_kernel(unsigned long long* __restrict__ keys, int M) {
    int i = blockIdx.x * blockDim.x + threadIdx.x;
    if (i < M) keys[i] = 0ULL;
}

// ---------------- m201-style 8-phase MFMA GEMM + fused argmax ----------------
// Effective GEMM: C = [2048*Ah | Ah | Al] x [Bh | Bl | Bh]^T, K = 3*512 = 1536.
#define BM 256
#define BN 256
#define BK 64            // halfs per K-tile
#define EH 512           // E in halfs (hardcoded fast path)
#define NT 24            // K-tiles total (1536/64)
#define BUFB 65536       // one buffer: 4 half-tiles x 16 KB
#define AH0_OFF 0
#define AH1_OFF 16384
#define BH0_OFF 32768
#define BH1_OFF 49152

#define WAIT4  asm volatile("s_waitcnt vmcnt(4)" ::: "memory")
#define WAIT0  asm volatile("s_waitcnt vmcnt(0)" ::: "memory")
#define NOWAIT (void)0

// one phase: quadrant (MH,NH); 16 MFMA; m201 barrier discipline
#define DO_PHASE(MH, NH, DO_READA, STAGE_STMT, WAIT_STMT)                        \
  {                                                                              \
    if (DO_READA) {                                                              \
      _Pragma("unroll")                                                          \
      for (int mm = 0; mm < 4; ++mm) {                                           \
        _Pragma("unroll")                                                        \
        for (int kk = 0; kk < 2; ++kk)                                           \
          af[mm][kk] = *(const f16x8*)(cb + ((MH) ? AH1_OFF : AH0_OFF)           \
                                       + aRB[mm] + cx[kk]);                      \
      }                                                                          \
    }                                                                            \
    f16x8 bf[2][2];                                                              \
    _Pragma("unroll")                                                            \
    for (int nn2 = 0; nn2 < 2; ++nn2) {                                          \
      _Pragma("unroll")                                                          \
      for (int kk = 0; kk < 2; ++kk)                                             \
        bf[nn2][kk] = *(const f16x8*)(cb + ((NH) ? BH1_OFF : BH0_OFF)            \
                                      + bCB[nn2] + cx[kk]);                      \
    }                                                                            \
    STAGE_STMT;                                                                  \
    __builtin_amdgcn_s_barrier();                                                \
    asm volatile("s_waitcnt lgkmcnt(0)" ::: "memory");                           \
    __builtin_amdgcn_sched_barrier(0);                                           \
    __builtin_amdgcn_s_setprio(1);                                               \
    _Pragma("unroll")                                                            \
    for (int mm = 0; mm < 4; ++mm) {                                             \
      _Pragma("unroll")                                                          \
      for (int nn2 = 0; nn2 < 2; ++nn2) {                                        \
        _Pragma("unroll")                                                        \
        for (int kk = 0; kk < 2; ++kk)                                           \
          acc[(MH)*4+mm][(NH)*2+nn2] = __builtin_amdgcn_mfma_f32_16x16x32_f16(   \
              af[mm][kk], bf[nn2][kk], acc[(MH)*4+mm][(NH)*2+nn2], 0, 0, 0);     \
      }                                                                          \
    }                                                                            \
    __builtin_amdgcn_s_setprio(0);                                               \
    WAIT_STMT;                                                                   \
    __builtin_amdgcn_s_barrier();                                                \
  }

__global__ __launch_bounds__(512, 2) void nn_mfma_pipe(
    const f16* __restrict__ Ahs, const f16* __restrict__ Ah, const f16* __restrict__ Al,
    const f16* __restrict__ Bh, const f16* __restrict__ Bl,
    const float* __restrict__ rinv, unsigned long long* __restrict__ keys,
    int M, int V)
{
    extern __shared__ char smem[];

    const int tid  = threadIdx.x;
    const int lane = tid & 63;
    const int w    = tid >> 6;      // wave 0..7
    const int wm   = w >> 2;        // 0..1
    const int wn   = w & 3;         // 0..3
    const int fr   = lane & 15;
    const int kg   = lane >> 4;     // 0..3

    // bijective XCD swizzle; mb fastest so consecutive blocks share B panel
    const int nwg = gridDim.x;
    const int bid = blockIdx.x;
    const int swz = ((nwg & 7) == 0) ? ((bid & 7) * (nwg >> 3) + (bid >> 3)) : bid;
    const int mblocks = M / BM;
    const int mb = swz % mblocks;
    const int nb = swz / mblocks;
    const int row0 = mb * BM;
    const int col0 = nb * BN;

    // ---- staging addressing (per wave: 2 gload_lds per half-tile) ----
    const int r8 = lane >> 3;             // 0..7
    const int sl = lane & 7;              // 16B slot
    const int xs = (sl ^ r8) * 8;         // pre-swizzled source col (halfs)
    int aoffL[2], boffL[2][2];
    #pragma unroll
    for (int i = 0; i < 2; ++i) {
        int ar = row0 + w * 16 + i * 8 + r8;          // A rows in half0; half1 adds 128
        aoffL[i] = ar * EH + xs;
        #pragma unroll
        for (int h = 0; h < 2; ++h) {
            int c = col0 + h * 128 + w * 16 + i * 8 + r8;
            if (c > V - 1) c = V - 1;
            boffL[h][i] = c * EH + xs;
        }
    }
    const int ldsd0 = (w * 16) * 128;
    const int ldsd1 = (w * 16 + 8) * 128;

    auto stage = [&](int bufi, int hsel, int tt) {
        const int seg  = tt >> 3;                    // 0,1,2
        const int koff = (tt & 7) * BK;              // halfs
        char* base = smem + (size_t)bufi * BUFB;
        if (hsel < 2) {       // A half hsel: seg0 Ahs, seg1 Ah, seg2 Al
            const f16* src = (seg == 0) ? Ahs : (seg == 1) ? Ah : Al;
            const f16* g = src + (size_t)hsel * 128 * EH + koff;
            char* d = base + (hsel ? AH1_OFF : AH0_OFF);
            llds16(g + aoffL[0], d + ldsd0);
            llds16(g + aoffL[1], d + ldsd1);
        } else {              // B half (hsel-2): seg0 Bh, seg1 Bl, seg2 Bh
            const int h = hsel - 2;
            const f16* src = (seg == 1) ? Bl : Bh;
            char* d = base + (h ? BH1_OFF : BH0_OFF);
            llds16(src + boffL[h][0] + koff, d + ldsd0);
            llds16(src + boffL[h][1] + koff, d + ldsd1);
        }
    };

    // ---- fragment read offsets (swizzled) ----
    int aRB[4], bCB[2], cx[2];
    #pragma unroll
    for (int mm = 0; mm < 4; ++mm) aRB[mm] = (wm * 64 + mm * 16 + fr) * 128;
    #pragma unroll
    for (int nn2 = 0; nn2 < 2; ++nn2) bCB[nn2] = (wn * 32 + nn2 * 16 + fr) * 128;
    #pragma unroll
    for (int kk = 0; kk < 2; ++kk) cx[kk] = ((kk * 4 + kg) ^ (fr & 7)) * 16;

    f32x4 acc[8][4];
    #pragma unroll
    for (int m = 0; m < 8; ++m)
        #pragma unroll
        for (int n = 0; n < 4; ++n) acc[m][n] = (f32x4){0.f, 0.f, 0.f, 0.f};

    // ---- prologue: stage tile 0 fully, drain ----
    #pragma unroll
    for (int h = 0; h < 4; ++h) stage(0, h, 0);
    WAIT0;
    __builtin_amdgcn_s_barrier();

    // ---- main loop: tiles 0..NT-2, staging t+1; vmcnt ledger 4-6 in flight ----
    #pragma unroll 1
    for (int t = 0; t < NT - 1; ++t) {
        char* cb = smem + (size_t)(t & 1) * BUFB;
        const int nbuf = (t + 1) & 1;
        const int tn = t + 1;
        f16x8 af[4][2];
        DO_PHASE(0, 0, 1, stage(nbuf, 0, tn), WAIT4)     // reads Ah0+Bh0; stage next Ah0
        DO_PHASE(0, 1, 0, stage(nbuf, 2, tn), WAIT4)     // reads Bh1;     stage next Bh0
        DO_PHASE(1, 1, 1, stage(nbuf, 3, tn), NOWAIT)    // reads Ah1;     stage next Bh1
        if (t < NT - 2) {
            DO_PHASE(1, 0, 0, stage(nbuf, 1, tn), WAIT4) // stage next Ah1
        } else {
            DO_PHASE(1, 0, 0, stage(nbuf, 1, tn), WAIT0) // full drain before last tile
        }
    }
    // ---- last tile: no staging, no vm waits ----
    {
        char* cb = smem + (size_t)((NT - 1) & 1) * BUFB;
        f16x8 af[4][2];
        DO_PHASE(0, 0, 1, NOWAIT, NOWAIT)
        DO_PHASE(0, 1, 0, NOWAIT, NOWAIT)
        DO_PHASE(1, 1, 1, NOWAIT, NOWAIT)
        DO_PHASE(1, 0, 0, NOWAIT, NOWAIT)
    }

    // ---- epilogue: s = acc * (rinv/2048); fused argmax ----
    float ri[4];
    #pragma unroll
    for (int nn = 0; nn < 4; ++nn) {
        int j = col0 + (nn >> 1) * 128 + wn * 32 + (nn & 1) * 16 + fr;
        ri[nn] = (j < V) ? rinv[j] : 0.f;
    }
    #pragma unroll
    for (int m = 0; m < 8; ++m) {
        #pragma unroll
        for (int r = 0; r < 4; ++r) {
            unsigned long long best = 0ULL;
            #pragma unroll
            for (int nn = 0; nn < 4; ++nn) {
                int j = col0 + (nn >> 1) * 128 + wn * 32 + (nn & 1) * 16 + fr;
                if (j < V) {
                    unsigned long long key = pack_key(acc[m][nn][r] * ri[nn], j);
                    if (key > best) best = key;
                }
            }
            #pragma unroll
            for (int o = 8; o > 0; o >>= 1) {
                unsigned long long other = __shfl_xor(best, o, 64);
                if (other > best) best = other;
            }
            if (fr == 0 && best != 0ULL) {
                int row = row0 + (m >> 2) * 128 + wm * 64 + (m & 3) * 16 + kg * 4 + r;
                atomicMax(&keys[row], best);
            }
        }
    }
}

// ---------------- extract indices ----------------
__global__ void extract_kernel(const unsigned long long* __restrict__ keys,
                               int* __restrict__ out, int M) {
    int i = blockIdx.x * blockDim.x + threadIdx.x;
    if (i < M) out[i] = (int)(~(unsigned)(keys[i] & 0xFFFFFFFFULL));
}

// ================= fallback fp32 path (round-0, validated) =================
__global__ void inv_norms_kernel(const float* __restrict__ emb,
                                 float* __restrict__ r, int V, int E) {
    int row  = blockIdx.x * (blockDim.x >> 6) + (threadIdx.x >> 6);
    int lane = threadIdx.x & 63;
    if (row >= V) return;
    const float4* p = reinterpret_cast<const float4*>(emb + (size_t)row * E);
    float ss = 0.f;
    int n4 = E >> 2;
    for (int i = lane; i < n4; i += 64) {
        float4 v = p[i];
        ss = fmaf(v.x, v.x, ss); ss = fmaf(v.y, v.y, ss);
        ss = fmaf(v.z, v.z, ss); ss = fmaf(v.w, v.w, ss);
    }
    #pragma unroll
    for (int o = 32; o > 0; o >>= 1) ss += __shfl_down(ss, o, 64);
    if (lane == 0) r[row] = 1.0f / sqrtf(ss);
}

#define FBM 128
#define FBN 128
#define FBK 32
#define LDSPAD 4

__global__ __launch_bounds__(256) void nn_gemm_argmax(
    const float* __restrict__ batch, const float* __restrict__ emb,
    const float* __restrict__ rinv, unsigned long long* __restrict__ keys,
    int M, int V, int E)
{
    __shared__ float As[FBK][FBM + LDSPAD];
    __shared__ float Bs[FBK][FBN + LDSPAD];
    const int tid = threadIdx.x;
    const int tx  = tid & 15;
    const int ty  = tid >> 4;
    const int row0 = blockIdx.y * FBM;
    const int col0 = blockIdx.x * FBN;
    float acc[8][8];
    #pragma unroll
    for (int i = 0; i < 8; ++i)
        #pragma unroll
        for (int j = 0; j < 8; ++j) acc[i][j] = 0.f;
    const int steps = E / FBK;
    for (int ks = 0; ks < steps; ++ks) {
        const int k0 = ks * FBK;
        #pragma unroll
        for (int it = 0; it < 4; ++it) {
            int idx = it * 256 + tid;
            int rr = idx >> 3, cc = idx & 7;
            float4 v = *reinterpret_cast<const float4*>(
                &batch[(size_t)(row0 + rr) * E + k0 + cc * 4]);
            As[cc*4+0][rr] = v.x; As[cc*4+1][rr] = v.y;
            As[cc*4+2][rr] = v.z; As[cc*4+3][rr] = v.w;
        }
        #pragma unroll
        for (int it = 0; it < 4; ++it) {
            int idx = it * 256 + tid;
            int rr = idx >> 3, cc = idx & 7;
            int j = col0 + rr;
            float4 v = make_float4(0.f,0.f,0.f,0.f);
            if (j < V)
                v = *reinterpret_cast<const float4*>(&emb[(size_t)j * E + k0 + cc * 4]);
            Bs[cc*4+0][rr] = v.x; Bs[cc*4+1][rr] = v.y;
            Bs[cc*4+2][rr] = v.z; Bs[cc*4+3][rr] = v.w;
        }
        __syncthreads();
        #pragma unroll
        for (int k = 0; k < FBK; ++k) {
            float4 a0 = *reinterpret_cast<const float4*>(&As[k][ty*8]);
            float4 a1 = *reinterpret_cast<const float4*>(&As[k][ty*8+4]);
            float4 b0 = *reinterpret_cast<const float4*>(&Bs[k][tx*8]);
            float4 b1 = *reinterpret_cast<const float4*>(&Bs[k][tx*8+4]);
            float a[8] = {a0.x,a0.y,a0.z,a0.w,a1.x,a1.y,a1.z,a1.w};
            float b[8] = {b0.x,b0.y,b0.z,b0.w,b1.x,b1.y,b1.z,b1.w};
            #pragma unroll
            for (int i = 0; i < 8; ++i)
                #pragma unroll
                for (int jj = 0; jj < 8; ++jj)
                    acc[i][jj] = fmaf(a[i], b[jj], acc[i][jj]);
        }
        __syncthreads();
    }
    #pragma unroll
    for (int i = 0; i < 8; ++i) {
        const int q = row0 + ty * 8 + i;
        unsigned long long best = 0ULL;
        #pragma unroll
        for (int jj = 0; jj < 8; ++jj) {
            int j = col0 + tx * 8 + jj;
            if (j < V) {
                unsigned long long key = pack_key(acc[i][jj] * rinv[j], j);
                if (key > best) best = key;
            }
        }
        #pragma unroll
        for (int o = 8; o > 0; o >>= 1) {
            unsigned long long other = __shfl_xor(best, o, 64);
            if (other > best) best = other;
        }
        if (tx == 0 && best != 0ULL) atomicMax(&keys[q], best);
    }
}

// ================= launch =================
extern "C" void kernel_launch(void* const* d_in, const int* in_sizes, int n_in,
                              void* d_out, int out_size, void* d_ws, size_t ws_size,
                              hipStream_t stream) {
    const float* batch = (const float*)d_in[0];  // [B,S,E] f32
    const float* emb   = (const float*)d_in[1];  // [V,E]   f32
    int* out = (int*)d_out;

    const int M = out_size;                 // 4096
    const int E = in_sizes[0] / M;          // 512
    const int V = in_sizes[1] / E;          // 50000

    auto al256 = [](size_t x) { return (x + 255) & ~(size_t)255; };
    size_t o_rinv = 0;
    size_t o_keys = al256(o_rinv + (size_t)V * 4);
    size_t o_Ahs  = al256(o_keys + (size_t)M * 8);
    size_t o_Ah   = al256(o_Ahs + (size_t)M * E * 2);
    size_t o_Al   = al256(o_Ah  + (size_t)M * E * 2);
    size_t o_Bh   = al256(o_Al  + (size_t)M * E * 2);
    size_t o_Bl   = al256(o_Bh  + (size_t)V * E * 2);
    size_t need   = al256(o_Bl  + (size_t)V * E * 2);

    unsigned long long* keys = (unsigned long long*)((char*)d_ws + o_keys);
    float* rinv = (float*)((char*)d_ws + o_rinv);

    if (ws_size >= need && E == EH && (M % BM) == 0) {
        f16* Ahs = (f16*)((char*)d_ws + o_Ahs);
        f16* Ah  = (f16*)((char*)d_ws + o_Ah);
        f16* Al  = (f16*)((char*)d_ws + o_Al);
        f16* Bh  = (f16*)((char*)d_ws + o_Bh);
        f16* Bl  = (f16*)((char*)d_ws + o_Bl);

        convert_emb_kernel<<<(V + 3) / 4, 256, 0, stream>>>(emb, Bh, Bl, rinv, V, E);
        convert_batch_kernel<<<(M + 3) / 4, 256, 0, stream>>>(batch, Ahs, Ah, Al, M, E);
        init_keys_kernel<<<(M + 255) / 256, 256, 0, stream>>>(keys, M);

        hipFuncSetAttribute((const void*)nn_mfma_pipe,
                            hipFuncAttributeMaxDynamicSharedMemorySize, 2 * BUFB);

        int nblocks = (M / BM) * ((V + BN - 1) / BN);   // 16 * 196 = 3136
        nn_mfma_pipe<<<nblocks, 512, 2 * BUFB, stream>>>(Ahs, Ah, Al, Bh, Bl,
                                                         rinv, keys, M, V);

        extract_kernel<<<(M + 255) / 256, 256, 0, stream>>>(keys, out, M);
    } else {
        inv_norms_kernel<<<(V + 3) / 4, 256, 0, stream>>>(emb, rinv, V, E);
        init_keys_kernel<<<(M + 255) / 256, 256, 0, stream>>>(keys, M);
        dim3 grid((V + FBN - 1) / FBN, M / FBM);
        nn_gemm_argmax<<<grid, 256, 0, stream>>>(batch, emb, rinv, keys, M, V, E);
        extract_kernel<<<(M + 255) / 256, 256, 0, stream>>>(keys, out, M);
    }
}

// Round 5
// 861.495 us; speedup vs baseline: 1.0280x; 1.0280x over previous
//
#include <hip/hip_runtime.h>
#include <stdint.h>

typedef _Float16 f16;
typedef _Float16 f16x4 __attribute__((ext_vector_type(4)));
typedef _Float16 f16x8 __attribute__((ext_vector_type(8)));
typedef float    f32x4 __attribute__((ext_vector_type(4)));

#define LO_SCALE 2048.0f

__device__ __forceinline__ void llds16(const void* g, void* l) {
    __builtin_amdgcn_global_load_lds(
        (const __attribute__((address_space(1))) void*)g,
        (__attribute__((address_space(3))) void*)l, 16, 0, 0);
}

__device__ __forceinline__ unsigned long long pack_key(float s, int j) {
    unsigned u = __float_as_uint(s);
    u = (u & 0x80000000u) ? ~u : (u | 0x80000000u);
    return ((unsigned long long)u << 32) | (unsigned)(~(unsigned)j);
}

// ---------------- convert emb -> Bh/Bl fp16 + rinv/2048 ----------------
__global__ void convert_emb_kernel(const float* __restrict__ emb,
                                   f16* __restrict__ bh, f16* __restrict__ bl,
                                   float* __restrict__ rinv, int V, int E) {
    int row  = blockIdx.x * (blockDim.x >> 6) + (threadIdx.x >> 6);
    int lane = threadIdx.x & 63;
    if (row >= V) return;
    const float4* p = (const float4*)(emb + (size_t)row * E);
    int n4 = E >> 2;
    float ss = 0.f;
    for (int i = lane; i < n4; i += 64) {
        float4 v = p[i];
        ss = fmaf(v.x, v.x, ss); ss = fmaf(v.y, v.y, ss);
        ss = fmaf(v.z, v.z, ss); ss = fmaf(v.w, v.w, ss);
    }
    #pragma unroll
    for (int o = 32; o > 0; o >>= 1) ss += __shfl_down(ss, o, 64);
    if (lane == 0) rinv[row] = 1.0f / (sqrtf(ss) * LO_SCALE);

    for (int i = lane; i < n4; i += 64) {
        float4 v = p[i];
        f16x4 h, l;
        h.x = (f16)v.x; l.x = (f16)((v.x - (float)h.x) * LO_SCALE);
        h.y = (f16)v.y; l.y = (f16)((v.y - (float)h.y) * LO_SCALE);
        h.z = (f16)v.z; l.z = (f16)((v.z - (float)h.z) * LO_SCALE);
        h.w = (f16)v.w; l.w = (f16)((v.w - (float)h.w) * LO_SCALE);
        *(f16x4*)&bh[(size_t)row * E + i * 4] = h;
        *(f16x4*)&bl[(size_t)row * E + i * 4] = l;
    }
}

// ---------------- convert batch -> Ahs(=2048*Ah)/Ah/Al ----------------
__global__ void convert_batch_kernel(const float* __restrict__ batch,
                                     f16* __restrict__ ahs, f16* __restrict__ ah,
                                     f16* __restrict__ al, int M, int E) {
    int row  = blockIdx.x * (blockDim.x >> 6) + (threadIdx.x >> 6);
    int lane = threadIdx.x & 63;
    if (row >= M) return;
    const float4* p = (const float4*)(batch + (size_t)row * E);
    int n4 = E >> 2;
    for (int i = lane; i < n4; i += 64) {
        float4 v = p[i];
        f16x4 h, hs, l;
        float t;
        h.x = (f16)v.x; t = (float)h.x * LO_SCALE; t = fminf(fmaxf(t, -65000.f), 65000.f);
        hs.x = (f16)t;  l.x = (f16)((v.x - (float)h.x) * LO_SCALE);
        h.y = (f16)v.y; t = (float)h.y * LO_SCALE; t = fminf(fmaxf(t, -65000.f), 65000.f);
        hs.y = (f16)t;  l.y = (f16)((v.y - (float)h.y) * LO_SCALE);
        h.z = (f16)v.z; t = (float)h.z * LO_SCALE; t = fminf(fmaxf(t, -65000.f), 65000.f);
        hs.z = (f16)t;  l.z = (f16)((v.z - (float)h.z) * LO_SCALE);
        h.w = (f16)v.w; t = (float)h.w * LO_SCALE; t = fminf(fmaxf(t, -65000.f), 65000.f);
        hs.w = (f16)t;  l.w = (f16)((v.w - (float)h.w) * LO_SCALE);
        *(f16x4*)&ahs[(size_t)row * E + i * 4] = hs;
        *(f16x4*)&ah [(size_t)row * E + i * 4] = h;
        *(f16x4*)&al [(size_t)row * E + i * 4] = l;
    }
}

// ---------------- init packed keys ----------------
__global__ void init_keys_kernel(unsigned long long* __restrict__ keys, int M) {
    int i = blockIdx.x * blockDim.x + threadIdx.x;
    if (i < M) keys[i] = 0ULL;
}

// ---------------- 4-phase/K-tile pipelined MFMA GEMM + fused argmax ----------------
// Effective GEMM: C = [2048*Ah | Ah | Al] x [Bh | Bl | Bh]^T, K = 3*512 = 1536.
#define BM 256
#define BN 256
#define BK 64            // halfs per K-tile
#define EH 512           // E in halfs (hardcoded fast path)
#define NT 24            // K-tiles total (1536/64)
#define BUFB 65536       // one buffer: 4 half-tiles x 16 KB
#define AH0_OFF 0
#define AH1_OFF 16384
#define BH0_OFF 32768
#define BH1_OFF 49152

#define WAIT4  asm volatile("s_waitcnt vmcnt(4)" ::: "memory")
#define WAIT0  asm volatile("s_waitcnt vmcnt(0)" ::: "memory")
#define LGK0   asm volatile("s_waitcnt lgkmcnt(0)" ::: "memory")

__global__ __launch_bounds__(512, 2) void nn_mfma_pipe(
    const f16* __restrict__ Ahs, const f16* __restrict__ Ah, const f16* __restrict__ Al,
    const f16* __restrict__ Bh, const f16* __restrict__ Bl,
    const float* __restrict__ rinv, unsigned long long* __restrict__ keys,
    int M, int V)
{
    extern __shared__ char smem[];

    const int tid  = threadIdx.x;
    const int lane = tid & 63;
    const int w    = tid >> 6;      // wave 0..7
    const int wm   = w >> 2;        // 0..1
    const int wn   = w & 3;         // 0..3
    const int fr   = lane & 15;
    const int kg   = lane >> 4;     // 0..3

    // bijective XCD swizzle; mb fastest so consecutive blocks share B panel
    const int nwg = gridDim.x;
    const int bid = blockIdx.x;
    const int swz = ((nwg & 7) == 0) ? ((bid & 7) * (nwg >> 3) + (bid >> 3)) : bid;
    const int mblocks = M / BM;
    const int mb = swz % mblocks;
    const int nb = swz / mblocks;
    const int row0 = mb * BM;
    const int col0 = nb * BN;

    // ---- staging addressing (per wave: 2 gload_lds per half-tile) ----
    const int r8 = lane >> 3;             // 0..7
    const int sl = lane & 7;              // 16B slot
    const int xs = (sl ^ r8) * 8;         // pre-swizzled source col (halfs)
    int aoffL[2], boffL[2][2];
    #pragma unroll
    for (int i = 0; i < 2; ++i) {
        int ar = row0 + w * 16 + i * 8 + r8;          // A rows in half0; half1 adds 128
        aoffL[i] = ar * EH + xs;
        #pragma unroll
        for (int h = 0; h < 2; ++h) {
            int c = col0 + h * 128 + w * 16 + i * 8 + r8;
            if (c > V - 1) c = V - 1;
            boffL[h][i] = c * EH + xs;
        }
    }
    const int ldsd0 = (w * 16) * 128;
    const int ldsd1 = (w * 16 + 8) * 128;

    auto stage = [&](int bufi, int hsel, int tt) {
        const int seg  = tt >> 3;                    // 0,1,2
        const int koff = (tt & 7) * BK;              // halfs
        char* base = smem + (size_t)bufi * BUFB;
        if (hsel < 2) {       // A half hsel: seg0 Ahs, seg1 Ah, seg2 Al
            const f16* src = (seg == 0) ? Ahs : (seg == 1) ? Ah : Al;
            const f16* g = src + (size_t)hsel * 128 * EH + koff;
            char* d = base + (hsel ? AH1_OFF : AH0_OFF);
            llds16(g + aoffL[0], d + ldsd0);
            llds16(g + aoffL[1], d + ldsd1);
        } else {              // B half (hsel-2): seg0 Bh, seg1 Bl, seg2 Bh
            const int h = hsel - 2;
            const f16* src = (seg == 1) ? Bl : Bh;
            char* d = base + (h ? BH1_OFF : BH0_OFF);
            llds16(src + boffL[h][0] + koff, d + ldsd0);
            llds16(src + boffL[h][1] + koff, d + ldsd1);
        }
    };

    // ---- fragment read offsets (swizzled) ----
    int aRB[4], bCB[2], cx[2];
    #pragma unroll
    for (int mm = 0; mm < 4; ++mm) aRB[mm] = (wm * 64 + mm * 16 + fr) * 128;
    #pragma unroll
    for (int nn2 = 0; nn2 < 2; ++nn2) bCB[nn2] = (wn * 32 + nn2 * 16 + fr) * 128;
    #pragma unroll
    for (int kk = 0; kk < 2; ++kk) cx[kk] = ((kk * 4 + kg) ^ (fr & 7)) * 16;

    f32x4 acc[8][4];
    #pragma unroll
    for (int m = 0; m < 8; ++m)
        #pragma unroll
        for (int n = 0; n < 4; ++n) acc[m][n] = (f32x4){0.f, 0.f, 0.f, 0.f};

    // ---- prologue: tile0 fully + A0(1), B1(1) in flight; verify tile0 ----
    stage(0, 0, 0); stage(0, 2, 0); stage(0, 1, 0); stage(0, 3, 0);
    stage(1, 0, 1); stage(1, 3, 1);
    WAIT4;
    __builtin_amdgcn_s_barrier();

    #define MFMA_Q(MH, NH, BFREG)                                                   \
        __builtin_amdgcn_s_setprio(1);                                              \
        _Pragma("unroll")                                                           \
        for (int mm = 0; mm < 4; ++mm) {                                            \
            _Pragma("unroll")                                                       \
            for (int nn2 = 0; nn2 < 2; ++nn2) {                                     \
                _Pragma("unroll")                                                   \
                for (int kk = 0; kk < 2; ++kk)                                      \
                    acc[(MH)*4+mm][(NH)*2+nn2] =                                    \
                        __builtin_amdgcn_mfma_f32_16x16x32_f16(                     \
                            af[mm][kk], BFREG[nn2][kk],                             \
                            acc[(MH)*4+mm][(NH)*2+nn2], 0, 0, 0);                   \
            }                                                                       \
        }                                                                           \
        __builtin_amdgcn_s_setprio(0);

    #pragma unroll 1
    for (int t = 0; t < NT; ++t) {
        char* cb = smem + (size_t)(t & 1) * BUFB;
        const int nb1 = (t + 1) & 1;      // buffer of tile t+1
        const int cbi = t & 1;            // buffer of tile t (== tile t+2)
        f16x8 af[4][2], bf0[2][2], bf1[2][2];

        // ---- p0 (Q00): read af<-A0, bf0<-B0; stage A1(t+1) ----
        #pragma unroll
        for (int mm = 0; mm < 4; ++mm)
            #pragma unroll
            for (int kk = 0; kk < 2; ++kk)
                af[mm][kk] = *(const f16x8*)(cb + AH0_OFF + aRB[mm] + cx[kk]);
        #pragma unroll
        for (int nn2 = 0; nn2 < 2; ++nn2)
            #pragma unroll
            for (int kk = 0; kk < 2; ++kk)
                bf0[nn2][kk] = *(const f16x8*)(cb + BH0_OFF + bCB[nn2] + cx[kk]);
        if (t + 1 < NT) stage(nb1, 1, t + 1);
        __builtin_amdgcn_s_barrier();
        LGK0;
        MFMA_Q(0, 0, bf0)
        __builtin_amdgcn_s_barrier();

        // ---- p1 (Q01): read bf1<-B1; stage B0(t+1) ----
        #pragma unroll
        for (int nn2 = 0; nn2 < 2; ++nn2)
            #pragma unroll
            for (int kk = 0; kk < 2; ++kk)
                bf1[nn2][kk] = *(const f16x8*)(cb + BH1_OFF + bCB[nn2] + cx[kk]);
        if (t + 1 < NT) stage(nb1, 2, t + 1);
        __builtin_amdgcn_s_barrier();
        LGK0;
        MFMA_Q(0, 1, bf1)
        __builtin_amdgcn_s_barrier();

        // ---- p2 (Q11): read af<-A1; stage A0(t+2) ----
        #pragma unroll
        for (int mm = 0; mm < 4; ++mm)
            #pragma unroll
            for (int kk = 0; kk < 2; ++kk)
                af[mm][kk] = *(const f16x8*)(cb + AH1_OFF + aRB[mm] + cx[kk]);
        if (t + 2 < NT) stage(cbi, 0, t + 2);
        __builtin_amdgcn_s_barrier();
        LGK0;
        MFMA_Q(1, 1, bf1)
        __builtin_amdgcn_s_barrier();

        // ---- p3 (Q10): no reads; stage B1(t+2); single counted vm-wait ----
        if (t + 2 < NT) stage(cbi, 3, t + 2);
        __builtin_amdgcn_s_barrier();
        MFMA_Q(1, 0, bf0)
        if (t + 2 < NT)      { WAIT4; }
        else if (t + 1 < NT) { WAIT0; }
        __builtin_amdgcn_s_barrier();
    }
    #undef MFMA_Q

    // ---- epilogue: s = acc * (rinv/2048); fused argmax ----
    float ri[4];
    #pragma unroll
    for (int nn = 0; nn < 4; ++nn) {
        int j = col0 + (nn >> 1) * 128 + wn * 32 + (nn & 1) * 16 + fr;
        ri[nn] = (j < V) ? rinv[j] : 0.f;
    }
    #pragma unroll
    for (int m = 0; m < 8; ++m) {
        #pragma unroll
        for (int r = 0; r < 4; ++r) {
            unsigned long long best = 0ULL;
            #pragma unroll
            for (int nn = 0; nn < 4; ++nn) {
                int j = col0 + (nn >> 1) * 128 + wn * 32 + (nn & 1) * 16 + fr;
                if (j < V) {
                    unsigned long long key = pack_key(acc[m][nn][r] * ri[nn], j);
                    if (key > best) best = key;
                }
            }
            #pragma unroll
            for (int o = 8; o > 0; o >>= 1) {
                unsigned long long other = __shfl_xor(best, o, 64);
                if (other > best) best = other;
            }
            if (fr == 0 && best != 0ULL) {
                int row = row0 + (m >> 2) * 128 + wm * 64 + (m & 3) * 16 + kg * 4 + r;
                atomicMax(&keys[row], best);
            }
        }
    }
}

// ---------------- extract indices ----------------
__global__ void extract_kernel(const unsigned long long* __restrict__ keys,
                               int* __restrict__ out, int M) {
    int i = blockIdx.x * blockDim.x + threadIdx.x;
    if (i < M) out[i] = (int)(~(unsigned)(keys[i] & 0xFFFFFFFFULL));
}

// ================= fallback fp32 path (round-0, validated) =================
__global__ void inv_norms_kernel(const float* __restrict__ emb,
                                 float* __restrict__ r, int V, int E) {
    int row  = blockIdx.x * (blockDim.x >> 6) + (threadIdx.x >> 6);
    int lane = threadIdx.x & 63;
    if (row >= V) return;
    const float4* p = reinterpret_cast<const float4*>(emb + (size_t)row * E);
    float ss = 0.f;
    int n4 = E >> 2;
    for (int i = lane; i < n4; i += 64) {
        float4 v = p[i];
        ss = fmaf(v.x, v.x, ss); ss = fmaf(v.y, v.y, ss);
        ss = fmaf(v.z, v.z, ss); ss = fmaf(v.w, v.w, ss);
    }
    #pragma unroll
    for (int o = 32; o > 0; o >>= 1) ss += __shfl_down(ss, o, 64);
    if (lane == 0) r[row] = 1.0f / sqrtf(ss);
}

#define FBM 128
#define FBN 128
#define FBK 32
#define LDSPAD 4

__global__ __launch_bounds__(256) void nn_gemm_argmax(
    const float* __restrict__ batch, const float* __restrict__ emb,
    const float* __restrict__ rinv, unsigned long long* __restrict__ keys,
    int M, int V, int E)
{
    __shared__ float As[FBK][FBM + LDSPAD];
    __shared__ float Bs[FBK][FBN + LDSPAD];
    const int tid = threadIdx.x;
    const int tx  = tid & 15;
    const int ty  = tid >> 4;
    const int row0 = blockIdx.y * FBM;
    const int col0 = blockIdx.x * FBN;
    float acc[8][8];
    #pragma unroll
    for (int i = 0; i < 8; ++i)
        #pragma unroll
        for (int j = 0; j < 8; ++j) acc[i][j] = 0.f;
    const int steps = E / FBK;
    for (int ks = 0; ks < steps; ++ks) {
        const int k0 = ks * FBK;
        #pragma unroll
        for (int it = 0; it < 4; ++it) {
            int idx = it * 256 + tid;
            int rr = idx >> 3, cc = idx & 7;
            float4 v = *reinterpret_cast<const float4*>(
                &batch[(size_t)(row0 + rr) * E + k0 + cc * 4]);
            As[cc*4+0][rr] = v.x; As[cc*4+1][rr] = v.y;
            As[cc*4+2][rr] = v.z; As[cc*4+3][rr] = v.w;
        }
        #pragma unroll
        for (int it = 0; it < 4; ++it) {
            int idx = it * 256 + tid;
            int rr = idx >> 3, cc = idx & 7;
            int j = col0 + rr;
            float4 v = make_float4(0.f,0.f,0.f,0.f);
            if (j < V)
                v = *reinterpret_cast<const float4*>(&emb[(size_t)j * E + k0 + cc * 4]);
            Bs[cc*4+0][rr] = v.x; Bs[cc*4+1][rr] = v.y;
            Bs[cc*4+2][rr] = v.z; Bs[cc*4+3][rr] = v.w;
        }
        __syncthreads();
        #pragma unroll
        for (int k = 0; k < FBK; ++k) {
            float4 a0 = *reinterpret_cast<const float4*>(&As[k][ty*8]);
            float4 a1 = *reinterpret_cast<const float4*>(&As[k][ty*8+4]);
            float4 b0 = *reinterpret_cast<const float4*>(&Bs[k][tx*8]);
            float4 b1 = *reinterpret_cast<const float4*>(&Bs[k][tx*8+4]);
            float a[8] = {a0.x,a0.y,a0.z,a0.w,a1.x,a1.y,a1.z,a1.w};
            float b[8] = {b0.x,b0.y,b0.z,b0.w,b1.x,b1.y,b1.z,b1.w};
            #pragma unroll
            for (int i = 0; i < 8; ++i)
                #pragma unroll
                for (int jj = 0; jj < 8; ++jj)
                    acc[i][jj] = fmaf(a[i], b[jj], acc[i][jj]);
        }
        __syncthreads();
    }
    #pragma unroll
    for (int i = 0; i < 8; ++i) {
        const int q = row0 + ty * 8 + i;
        unsigned long long best = 0ULL;
        #pragma unroll
        for (int jj = 0; jj < 8; ++jj) {
            int j = col0 + tx * 8 + jj;
            if (j < V) {
                unsigned long long key = pack_key(acc[i][jj] * rinv[j], j);
                if (key > best) best = key;
            }
        }
        #pragma unroll
        for (int o = 8; o > 0; o >>= 1) {
            unsigned long long other = __shfl_xor(best, o, 64);
            if (other > best) best = other;
        }
        if (tx == 0 && best != 0ULL) atomicMax(&keys[q], best);
    }
}

// ================= launch =================
extern "C" void kernel_launch(void* const* d_in, const int* in_sizes, int n_in,
                              void* d_out, int out_size, void* d_ws, size_t ws_size,
                              hipStream_t stream) {
    const float* batch = (const float*)d_in[0];  // [B,S,E] f32
    const float* emb   = (const float*)d_in[1];  // [V,E]   f32
    int* out = (int*)d_out;

    const int M = out_size;                 // 4096
    const int E = in_sizes[0] / M;          // 512
    const int V = in_sizes[1] / E;          // 50000

    auto al256 = [](size_t x) { return (x + 255) & ~(size_t)255; };
    size_t o_rinv = 0;
    size_t o_keys = al256(o_rinv + (size_t)V * 4);
    size_t o_Ahs  = al256(o_keys + (size_t)M * 8);
    size_t o_Ah   = al256(o_Ahs + (size_t)M * E * 2);
    size_t o_Al   = al256(o_Ah  + (size_t)M * E * 2);
    size_t o_Bh   = al256(o_Al  + (size_t)M * E * 2);
    size_t o_Bl   = al256(o_Bh  + (size_t)V * E * 2);
    size_t need   = al256(o_Bl  + (size_t)V * E * 2);

    unsigned long long* keys = (unsigned long long*)((char*)d_ws + o_keys);
    float* rinv = (float*)((char*)d_ws + o_rinv);

    if (ws_size >= need && E == EH && (M % BM) == 0) {
        f16* Ahs = (f16*)((char*)d_ws + o_Ahs);
        f16* Ah  = (f16*)((char*)d_ws + o_Ah);
        f16* Al  = (f16*)((char*)d_ws + o_Al);
        f16* Bh  = (f16*)((char*)d_ws + o_Bh);
        f16* Bl  = (f16*)((char*)d_ws + o_Bl);

        convert_emb_kernel<<<(V + 3) / 4, 256, 0, stream>>>(emb, Bh, Bl, rinv, V, E);
        convert_batch_kernel<<<(M + 3) / 4, 256, 0, stream>>>(batch, Ahs, Ah, Al, M, E);
        init_keys_kernel<<<(M + 255) / 256, 256, 0, stream>>>(keys, M);

        hipFuncSetAttribute((const void*)nn_mfma_pipe,
                            hipFuncAttributeMaxDynamicSharedMemorySize, 2 * BUFB);

        int nblocks = (M / BM) * ((V + BN - 1) / BN);   // 16 * 196 = 3136
        nn_mfma_pipe<<<nblocks, 512, 2 * BUFB, stream>>>(Ahs, Ah, Al, Bh, Bl,
                                                         rinv, keys, M, V);

        extract_kernel<<<(M + 255) / 256, 256, 0, stream>>>(keys, out, M);
    } else {
        inv_norms_kernel<<<(V + 3) / 4, 256, 0, stream>>>(emb, rinv, V, E);
        init_keys_kernel<<<(M + 255) / 256, 256, 0, stream>>>(keys, M);
        dim3 grid((V + FBN - 1) / FBN, M / FBM);
        nn_gemm_argmax<<<grid, 256, 0, stream>>>(batch, emb, rinv, keys, M, V, E);
        extract_kernel<<<(M + 255) / 256, 256, 0, stream>>>(keys, out, M);
    }
}